// Round 4
// baseline (1478.638 us; speedup 1.0000x reference)
//
#include <hip/hip_runtime.h>

#define NN 30000
#define NE 480000
#define NR 16
#define D  128
#define NT 200000
#define AST 132                 // padded LDS row stride (floats)
#define NBLK 235                // ceil(NN/128)
#define NBINS (NBLK * NR)       // 3760
#define PF 16                   // prefetched edges per wave per relation

// ---------------- prep kernels ----------------

__global__ void k_gather_x(const float* __restrict__ node_emb,
                           const int* __restrict__ local_nodes,
                           float* __restrict__ x) {
  int i4 = blockIdx.x * blockDim.x + threadIdx.x;
  if (i4 >= NN * (D / 4)) return;
  int n = i4 >> 5, c = i4 & 31;
  int src = local_nodes[n];
  reinterpret_cast<float4*>(x)[i4] =
      reinterpret_cast<const float4*>(node_emb)[(size_t)src * 32 + c];
}

__global__ void k_hist_bins(const int* __restrict__ ei, const int* __restrict__ et,
                            int* __restrict__ bins) {
  int e = blockIdx.x * blockDim.x + threadIdx.x;
  if (e >= NE) return;
  int d = ei[NE + e], r = et[e];
  atomicAdd(&bins[(d >> 7) * NR + r], 1);
}

__global__ void k_scan_bins(const int* __restrict__ bins, int* __restrict__ off,
                            int* __restrict__ cur) {
  __shared__ int ps[1024];
  const int t = threadIdx.x;
  const int base = t * 4;
  int c[4], s0 = 0;
#pragma unroll
  for (int u = 0; u < 4; ++u) {
    int b = base + u;
    c[u] = (b < NBINS) ? bins[b] : 0;
    s0 += c[u];
  }
  ps[t] = s0;
  __syncthreads();
  for (int dstep = 1; dstep < 1024; dstep <<= 1) {
    int v = (t >= dstep) ? ps[t - dstep] : 0;
    __syncthreads();
    ps[t] += v;
    __syncthreads();
  }
  int ex = ps[t] - s0;
#pragma unroll
  for (int u = 0; u < 4; ++u) {
    int b = base + u;
    if (b <= NBINS) {
      off[b] = ex;
      if (b < NBINS) cur[b] = ex;
    }
    ex += c[u];
  }
}

__global__ void k_fill(const int* __restrict__ ei, const int* __restrict__ et,
                       int* __restrict__ cur, int* __restrict__ srt,
                       float* __restrict__ deg) {
  int e = blockIdx.x * blockDim.x + threadIdx.x;
  if (e >= NE) return;
  int s = ei[e], d = ei[NE + e], r = et[e];
  int p = atomicAdd(&cur[(d >> 7) * NR + r], 1);
  srt[p] = ((d & 127) << 16) | s;        // src < 2^15, dst_low < 2^7 -> sign bit clear
  atomicAdd(&deg[d], 1.0f);
}

// WT[k][o] = W[o][k] for the self-loop weights (torch Linear layout -> k-major)
__global__ void k_transposeW(const float* __restrict__ W0, const float* __restrict__ W1,
                             float* __restrict__ T0, float* __restrict__ T1) {
  const float* W = blockIdx.x ? W1 : W0;
  float* T = blockIdx.x ? T1 : T0;
  for (int idx = threadIdx.x; idx < D * D; idx += 256) {
    int o = idx >> 7, k = idx & 127;
    T[k * D + o] = W[idx];
  }
}

// ---------------- fused RGCN layer ----------------
// acc[8][4] micro-tile: rows ty+16j (ty=tid>>5), cols 4tx..4tx+3 (tx=tid&31).
// W is read directly from global (L2-hot, broadcast across blocks).

__device__ __forceinline__ void gemm_tile(const float (*S)[AST],
                                          const float* __restrict__ Wg,
                                          int tx, int ty, float acc[8][4]) {
  const float4* __restrict__ W4 = reinterpret_cast<const float4*>(Wg);
#pragma unroll 8
  for (int k = 0; k < D; k += 4) {
    float4 a[8];
#pragma unroll
    for (int j = 0; j < 8; ++j)
      a[j] = *reinterpret_cast<const float4*>(&S[ty + 16 * j][k]);
    float4 w[4];
#pragma unroll
    for (int kk = 0; kk < 4; ++kk) w[kk] = W4[(k + kk) * 32 + tx];
#pragma unroll
    for (int kk = 0; kk < 4; ++kk) {
#pragma unroll
      for (int j = 0; j < 8; ++j) {
        float av = (kk == 0) ? a[j].x : (kk == 1) ? a[j].y
                 : (kk == 2) ? a[j].z : a[j].w;
        acc[j][0] += av * w[kk].x;
        acc[j][1] += av * w[kk].y;
        acc[j][2] += av * w[kk].z;
        acc[j][3] += av * w[kk].w;
      }
    }
  }
}

__launch_bounds__(512, 2)
__global__ void k_fused(const float* __restrict__ x, const float* __restrict__ Wrel,
                        const float* __restrict__ WT, const float* __restrict__ Wb,
                        const int* __restrict__ srt, const int* __restrict__ off,
                        const float* __restrict__ deg, float* __restrict__ xo) {
  __shared__ float S[D][AST];            // 67,584 B (only LDS use)
  const int nb = blockIdx.x;
  const int row0 = nb * D;
  const int tx = threadIdx.x & 31, ty = threadIdx.x >> 5;
  const int wave = threadIdx.x >> 6, lane = threadIdx.x & 63;
  const float2* __restrict__ x2 = reinterpret_cast<const float2*>(x);

  float acc[8][4];
#pragma unroll
  for (int j = 0; j < 8; ++j)
#pragma unroll
    for (int m = 0; m < 4; ++m) acc[j][m] = 0.f;

  int pv[PF];
  float2 pvv[PF];

  auto zeroS = [&]() {
    float4* S4 = reinterpret_cast<float4*>(&S[0][0]);
#pragma unroll
    for (int t = 0; t < 9; ++t) {
      int idx = threadIdx.x + 512 * t;   // 4224 float4 total
      if (idx < D * AST / 4) S4[idx] = make_float4(0.f, 0.f, 0.f, 0.f);
    }
  };
  // issue-early: edge ids + x-rows for a bin into registers (latency hidden by GEMM)
  auto loadE = [&](int b) {
    const int base = off[b], end = off[b + 1];
#pragma unroll
    for (int t = 0; t < PF; ++t) {
      int i = base + wave + 8 * t;
      pv[t] = (i < end) ? srt[i] : -1;
    }
#pragma unroll
    for (int t = 0; t < PF; ++t)
      pvv[t] = (pv[t] >= 0) ? x2[(size_t)(pv[t] & 0xFFFF) * 64 + lane]
                            : make_float2(0.f, 0.f);
  };
  // write-late: deposit into S with LDS float atomics (2-way bank = free)
  auto depositE = [&](int b) {
#pragma unroll
    for (int t = 0; t < PF; ++t)
      if (pv[t] >= 0) {
        int dl = pv[t] >> 16;
        atomicAdd(&S[dl][2 * lane], pvv[t].x);
        atomicAdd(&S[dl][2 * lane + 1], pvv[t].y);
      }
    // leftover edges (bin > 8*PF), rare
    const int end = off[b + 1];
    for (int i = off[b] + 8 * PF + wave; i < end; i += 8) {
      int p = srt[i];
      float2 vv = x2[(size_t)(p & 0xFFFF) * 64 + lane];
      atomicAdd(&S[p >> 16][2 * lane], vv.x);
      atomicAdd(&S[p >> 16][2 * lane + 1], vv.y);
    }
  };

  // prologue: zero S, gather relation 0
  zeroS();
  __syncthreads();
  loadE(nb * NR);
  depositE(nb * NR);

  for (int r = 0; r < NR; ++r) {
    __syncthreads();                     // deposits for r visible
    if (r + 1 < NR) loadE(nb * NR + r + 1);   // in-flight across the GEMM
    gemm_tile(S, Wrel + (size_t)r * D * D, tx, ty, acc);
    __syncthreads();                     // all S reads done
    zeroS();
    __syncthreads();                     // zero visible
    if (r + 1 < NR) depositE(nb * NR + r + 1);
  }

  // scale message aggregate by 1/deg (before self term)
#pragma unroll
  for (int j = 0; j < 8; ++j) {
    int row = row0 + ty + 16 * j;
    float dv = (row < NN) ? deg[row] : 1.f;
    float inv = 1.f / fmaxf(dv, 1.f);
#pragma unroll
    for (int m = 0; m < 4; ++m) acc[j][m] *= inv;
  }

  // self phase: stage x rows into S (S already zeroed+synced), acc += x @ WT
#pragma unroll
  for (int t = 0; t < 8; ++t) {
    int idx = threadIdx.x + 512 * t;     // 4096 float4 of payload
    int rw = idx >> 5, c = idx & 31;
    float4 vv = make_float4(0.f, 0.f, 0.f, 0.f);
    if (row0 + rw < NN)
      vv = reinterpret_cast<const float4*>(x)[(size_t)(row0 + rw) * 32 + c];
    *reinterpret_cast<float4*>(&S[rw][4 * c]) = vv;
  }
  __syncthreads();
  gemm_tile(S, WT, tx, ty, acc);

  // epilogue: relu(acc + bias), one float4 store per row
  const float4 bb = reinterpret_cast<const float4*>(Wb)[tx];
#pragma unroll
  for (int j = 0; j < 8; ++j) {
    int row = row0 + ty + 16 * j;
    if (row < NN) {
      float4 o;
      o.x = fmaxf(acc[j][0] + bb.x, 0.f);
      o.y = fmaxf(acc[j][1] + bb.y, 0.f);
      o.z = fmaxf(acc[j][2] + bb.z, 0.f);
      o.w = fmaxf(acc[j][3] + bb.w, 0.f);
      reinterpret_cast<float4*>(xo + (size_t)row * D)[tx] = o;
    }
  }
}

// ---------------- DistMult scoring ----------------

__global__ void k_score(const float* __restrict__ x, const float* __restrict__ rel,
                        const int* __restrict__ hh, const int* __restrict__ rr,
                        const int* __restrict__ tt, float* __restrict__ out) {
  int gw = (blockIdx.x * blockDim.x + threadIdx.x) >> 6;
  int lane = threadIdx.x & 63;
  int nw = (gridDim.x * blockDim.x) >> 6;
  for (int i = gw; i < NT; i += nw) {
    const float2* ph = reinterpret_cast<const float2*>(x + (size_t)hh[i] * D);
    const float2* pr = reinterpret_cast<const float2*>(rel + (size_t)rr[i] * D);
    const float2* pt = reinterpret_cast<const float2*>(x + (size_t)tt[i] * D);
    float2 a = ph[lane], b = pr[lane], c = pt[lane];
    float v = a.x * b.x * c.x + a.y * b.y * c.y;
#pragma unroll
    for (int m = 32; m; m >>= 1) v += __shfl_xor(v, m);
    if (lane == 0) out[i] = v;
  }
}

// ---------------- launch ----------------

extern "C" void kernel_launch(void* const* d_in, const int* in_sizes, int n_in,
                              void* d_out, int out_size, void* d_ws, size_t ws_size,
                              hipStream_t stream) {
  const float* node_emb = (const float*)d_in[0];
  const float* rel_emb  = (const float*)d_in[1];
  const float* W_rel0   = (const float*)d_in[2];
  const float* Wself_w0 = (const float*)d_in[3];
  const float* Wself_b0 = (const float*)d_in[4];
  const float* W_rel1   = (const float*)d_in[5];
  const float* Wself_w1 = (const float*)d_in[6];
  const float* Wself_b1 = (const float*)d_in[7];
  const int* local_nodes = (const int*)d_in[8];
  const int* edge_index  = (const int*)d_in[9];
  const int* edge_type   = (const int*)d_in[10];
  const int* h_loc = (const int*)d_in[11];
  const int* r_ids = (const int*)d_in[12];
  const int* t_loc = (const int*)d_in[13];
  float* out = (float*)d_out;

  // workspace layout (bytes)
  char* ws = (char*)d_ws;
  float* x_a = (float*)(ws + 0);             // 15,360,000
  float* x_b = (float*)(ws + 15360000);      // 15,360,000
  float* WT0 = (float*)(ws + 30720000);      //     65,536
  float* WT1 = (float*)(ws + 30785536);      //     65,536
  float* deg = (float*)(ws + 30851072);      //    120,000
  int* bins  = (int*)(ws + 30971072);        //     15,040
  int* off   = (int*)(ws + 30986112);        //     15,044 (3761 ints)
  int* cur   = (int*)(ws + 31001156);        //     15,040
  int* srt   = (int*)(ws + 31016196);        //  1,920,000
  if (ws_size < (size_t)32936196) return;

  // zero deg + bins (contiguous); off/cur/srt fully overwritten downstream
  hipMemsetAsync(ws + 30851072, 0, 135040, stream);

  k_gather_x<<<3750, 256, 0, stream>>>(node_emb, local_nodes, x_a);
  k_hist_bins<<<1875, 256, 0, stream>>>(edge_index, edge_type, bins);
  k_scan_bins<<<1, 1024, 0, stream>>>(bins, off, cur);
  k_fill<<<1875, 256, 0, stream>>>(edge_index, edge_type, cur, srt, deg);
  k_transposeW<<<2, 256, 0, stream>>>(Wself_w0, Wself_w1, WT0, WT1);

  k_fused<<<NBLK, 512, 0, stream>>>(x_a, W_rel0, WT0, Wself_b0, srt, off, deg, x_b);
  k_fused<<<NBLK, 512, 0, stream>>>(x_b, W_rel1, WT1, Wself_b1, srt, off, deg, x_a);

  k_score<<<1024, 256, 0, stream>>>(x_a, rel_emb, h_loc, r_ids, t_loc, out);
}

// Round 6
// 1417.076 us; speedup vs baseline: 1.0434x; 1.0434x over previous
//
#include <hip/hip_runtime.h>

#define NN 30000
#define NE 480000
#define NR 16
#define D  128
#define NT 200000
#define BR 64                   // dst rows per block
#define NBLK 469                // ceil(NN/64)
#define NBINS (NBLK * NR)       // 7504
#define PF 24                   // prefetched edges per wave per relation (4 waves -> 96)

// ---------------- prep kernels ----------------

__global__ void k_gather_x(const float* __restrict__ node_emb,
                           const int* __restrict__ local_nodes,
                           float* __restrict__ x) {
  int i4 = blockIdx.x * blockDim.x + threadIdx.x;
  if (i4 >= NN * (D / 4)) return;
  int n = i4 >> 5, c = i4 & 31;
  int src = local_nodes[n];
  reinterpret_cast<float4*>(x)[i4] =
      reinterpret_cast<const float4*>(node_emb)[(size_t)src * 32 + c];
}

__global__ void k_hist_bins(const int* __restrict__ ei, const int* __restrict__ et,
                            int* __restrict__ bins) {
  int e = blockIdx.x * blockDim.x + threadIdx.x;
  if (e >= NE) return;
  int d = ei[NE + e], r = et[e];
  atomicAdd(&bins[(d >> 6) * NR + r], 1);
}

__global__ void k_scan_bins(const int* __restrict__ bins, int* __restrict__ off,
                            int* __restrict__ cur) {
  __shared__ int ps[1024];
  const int t = threadIdx.x;
  const int base = t * 8;
  int c[8], s0 = 0;
#pragma unroll
  for (int u = 0; u < 8; ++u) {
    int b = base + u;
    c[u] = (b < NBINS) ? bins[b] : 0;
    s0 += c[u];
  }
  ps[t] = s0;
  __syncthreads();
  for (int dstep = 1; dstep < 1024; dstep <<= 1) {
    int v = (t >= dstep) ? ps[t - dstep] : 0;
    __syncthreads();
    ps[t] += v;
    __syncthreads();
  }
  int ex = ps[t] - s0;
#pragma unroll
  for (int u = 0; u < 8; ++u) {
    int b = base + u;
    if (b <= NBINS) {
      off[b] = ex;
      if (b < NBINS) cur[b] = ex;
    }
    ex += c[u];
  }
}

__global__ void k_fill(const int* __restrict__ ei, const int* __restrict__ et,
                       int* __restrict__ cur, int* __restrict__ srt,
                       float* __restrict__ deg) {
  int e = blockIdx.x * blockDim.x + threadIdx.x;
  if (e >= NE) return;
  int s = ei[e], d = ei[NE + e], r = et[e];
  int p = atomicAdd(&cur[(d >> 6) * NR + r], 1);
  srt[p] = ((d & 63) << 16) | s;         // src < 2^15, dst_low < 2^6 -> sign bit clear
  atomicAdd(&deg[d], 1.0f);
}

// WT[k][o] = W[o][k] for the self-loop weights (torch Linear layout -> k-major)
__global__ void k_transposeW(const float* __restrict__ W0, const float* __restrict__ W1,
                             float* __restrict__ T0, float* __restrict__ T1) {
  const float* W = blockIdx.x ? W1 : W0;
  float* T = blockIdx.x ? T1 : T0;
  for (int idx = threadIdx.x; idx < D * D; idx += 256) {
    int o = idx >> 7, k = idx & 127;
    T[k * D + o] = W[idx];
  }
}

// ---------------- fused RGCN layer ----------------
// 64-row tile, 256 threads, acc[8][4]: rows ty+8j (ty=tid>>5 in 0..7),
// cols 4tx..4tx+3 (tx=tid&31). W read directly from global (L2-hot broadcast).
// S double-buffered: deposits for r+1 overlap GEMM of r; 2 barriers/relation.

__device__ __forceinline__ void gemm_tile(const float (*S)[D],
                                          const float* __restrict__ Wg,
                                          int tx, int ty, float acc[8][4]) {
  const float4* __restrict__ W4 = reinterpret_cast<const float4*>(Wg);
#pragma unroll 8
  for (int k = 0; k < D; k += 4) {
    float4 a[8];
#pragma unroll
    for (int j = 0; j < 8; ++j)
      a[j] = *reinterpret_cast<const float4*>(&S[ty + 8 * j][k]);   // half-wave broadcast
    float4 w[4];
#pragma unroll
    for (int kk = 0; kk < 4; ++kk) w[kk] = W4[(k + kk) * 32 + tx];
#pragma unroll
    for (int kk = 0; kk < 4; ++kk) {
#pragma unroll
      for (int j = 0; j < 8; ++j) {
        float av = (kk == 0) ? a[j].x : (kk == 1) ? a[j].y
                 : (kk == 2) ? a[j].z : a[j].w;
        acc[j][0] += av * w[kk].x;
        acc[j][1] += av * w[kk].y;
        acc[j][2] += av * w[kk].z;
        acc[j][3] += av * w[kk].w;
      }
    }
  }
}

__launch_bounds__(256, 2)
__global__ void k_fused(const float* __restrict__ x, const float* __restrict__ Wrel,
                        const float* __restrict__ WT, const float* __restrict__ Wb,
                        const int* __restrict__ srt, const int* __restrict__ off,
                        const float* __restrict__ deg, float* __restrict__ xo) {
  __shared__ float S[2][BR][D];          // 65,536 B
  const int nb = blockIdx.x;
  const int row0 = nb * BR;
  const int tx = threadIdx.x & 31, ty = threadIdx.x >> 5;
  const int wave = threadIdx.x >> 6, lane = threadIdx.x & 63;
  const float2* __restrict__ x2 = reinterpret_cast<const float2*>(x);

  float acc[8][4];
#pragma unroll
  for (int j = 0; j < 8; ++j)
#pragma unroll
    for (int m = 0; m < 4; ++m) acc[j][m] = 0.f;

  int pv[PF];
  float2 pvv[PF];

  auto zeroS = [&](int c) {
    float4* S4 = reinterpret_cast<float4*>(&S[c][0][0]);
#pragma unroll
    for (int t = 0; t < 8; ++t)
      S4[threadIdx.x + 256 * t] = make_float4(0.f, 0.f, 0.f, 0.f);   // 2048 total
  };
  // issue-early: edge ids + x-rows for bin b into registers
  auto loadE = [&](int b) {
    const int base = off[b], end = off[b + 1];
#pragma unroll
    for (int t = 0; t < PF; ++t) {
      int i = base + wave + 4 * t;
      pv[t] = (i < end) ? srt[i] : -1;
    }
#pragma unroll
    for (int t = 0; t < PF; ++t)
      pvv[t] = (pv[t] >= 0) ? x2[(size_t)(pv[t] & 0xFFFF) * 64 + lane]
                            : make_float2(0.f, 0.f);
  };
  // write-late: deposit into S[c] with LDS float atomics (2-way bank = free)
  auto depositE = [&](int b, int c) {
#pragma unroll
    for (int t = 0; t < PF; ++t)
      if (pv[t] >= 0) {
        int dl = pv[t] >> 16;
        atomicAdd(&S[c][dl][2 * lane], pvv[t].x);
        atomicAdd(&S[c][dl][2 * lane + 1], pvv[t].y);
      }
    const int end = off[b + 1];                  // leftover edges (bin > 4*PF), rare
    for (int i = off[b] + 4 * PF + wave; i < end; i += 4) {
      int p = srt[i];
      float2 vv = x2[(size_t)(p & 0xFFFF) * 64 + lane];
      atomicAdd(&S[c][p >> 16][2 * lane], vv.x);
      atomicAdd(&S[c][p >> 16][2 * lane + 1], vv.y);
    }
  };

  // prologue: zero both buffers, gather relation 0 into S[0]
  zeroS(0);
  zeroS(1);
  __syncthreads();
  loadE(nb * NR);
  depositE(nb * NR, 0);

  int cur = 0;
  for (int r = 0; r < NR; ++r) {
    __syncthreads();                     // B1: deposits for r (S[cur]) visible
    if (r + 1 < NR) loadE(nb * NR + r + 1);      // gathers in flight across GEMM
    gemm_tile(S[cur], Wrel + (size_t)r * D * D, tx, ty, acc);
    if (r + 1 < NR) depositE(nb * NR + r + 1, cur ^ 1);
    __syncthreads();                     // B2: S[cur] reads + S[cur^1] deposits done
    if (r + 2 < NR) zeroS(cur);          // prepare S[cur] for relation r+2 deposits
    cur ^= 1;
  }

  // scale message aggregate by 1/deg (before self term)
#pragma unroll
  for (int j = 0; j < 8; ++j) {
    int row = row0 + ty + 8 * j;
    float dv = (row < NN) ? deg[row] : 1.f;
    float inv = 1.f / fmaxf(dv, 1.f);
#pragma unroll
    for (int m = 0; m < 4; ++m) acc[j][m] *= inv;
  }

  // self phase: stage x rows into S[0] (fully overwritten), acc += x @ WT
#pragma unroll
  for (int t = 0; t < 8; ++t) {
    int idx = threadIdx.x + 256 * t;     // 2048 float4
    int rw = idx >> 5, c = idx & 31;
    float4 vv = make_float4(0.f, 0.f, 0.f, 0.f);
    if (row0 + rw < NN)
      vv = reinterpret_cast<const float4*>(x)[(size_t)(row0 + rw) * 32 + c];
    *reinterpret_cast<float4*>(&S[0][rw][4 * c]) = vv;
  }
  __syncthreads();
  gemm_tile(S[0], WT, tx, ty, acc);

  // epilogue: relu(acc + bias), one float4 store per row
  const float4 bb = reinterpret_cast<const float4*>(Wb)[tx];
#pragma unroll
  for (int j = 0; j < 8; ++j) {
    int row = row0 + ty + 8 * j;
    if (row < NN) {
      float4 o;
      o.x = fmaxf(acc[j][0] + bb.x, 0.f);
      o.y = fmaxf(acc[j][1] + bb.y, 0.f);
      o.z = fmaxf(acc[j][2] + bb.z, 0.f);
      o.w = fmaxf(acc[j][3] + bb.w, 0.f);
      reinterpret_cast<float4*>(xo + (size_t)row * D)[tx] = o;
    }
  }
}

// ---------------- DistMult scoring ----------------

__global__ void k_score(const float* __restrict__ x, const float* __restrict__ rel,
                        const int* __restrict__ hh, const int* __restrict__ rr,
                        const int* __restrict__ tt, float* __restrict__ out) {
  int gw = (blockIdx.x * blockDim.x + threadIdx.x) >> 6;
  int lane = threadIdx.x & 63;
  int nw = (gridDim.x * blockDim.x) >> 6;
  for (int i = gw; i < NT; i += nw) {
    const float2* ph = reinterpret_cast<const float2*>(x + (size_t)hh[i] * D);
    const float2* pr = reinterpret_cast<const float2*>(rel + (size_t)rr[i] * D);
    const float2* pt = reinterpret_cast<const float2*>(x + (size_t)tt[i] * D);
    float2 a = ph[lane], b = pr[lane], c = pt[lane];
    float v = a.x * b.x * c.x + a.y * b.y * c.y;
#pragma unroll
    for (int m = 32; m; m >>= 1) v += __shfl_xor(v, m);
    if (lane == 0) out[i] = v;
  }
}

// ---------------- launch ----------------

extern "C" void kernel_launch(void* const* d_in, const int* in_sizes, int n_in,
                              void* d_out, int out_size, void* d_ws, size_t ws_size,
                              hipStream_t stream) {
  const float* node_emb = (const float*)d_in[0];
  const float* rel_emb  = (const float*)d_in[1];
  const float* W_rel0   = (const float*)d_in[2];
  const float* Wself_w0 = (const float*)d_in[3];
  const float* Wself_b0 = (const float*)d_in[4];
  const float* W_rel1   = (const float*)d_in[5];
  const float* Wself_w1 = (const float*)d_in[6];
  const float* Wself_b1 = (const float*)d_in[7];
  const int* local_nodes = (const int*)d_in[8];
  const int* edge_index  = (const int*)d_in[9];
  const int* edge_type   = (const int*)d_in[10];
  const int* h_loc = (const int*)d_in[11];
  const int* r_ids = (const int*)d_in[12];
  const int* t_loc = (const int*)d_in[13];
  float* out = (float*)d_out;

  // workspace layout (bytes)
  char* ws = (char*)d_ws;
  float* x_a = (float*)(ws + 0);             // 15,360,000
  float* x_b = (float*)(ws + 15360000);      // 15,360,000
  float* WT0 = (float*)(ws + 30720000);      //     65,536
  float* WT1 = (float*)(ws + 30785536);      //     65,536
  float* deg = (float*)(ws + 30851072);      //    120,000
  int* bins  = (int*)(ws + 30971072);        //     30,016
  int* off   = (int*)(ws + 31001088);        //     30,020 (7505 ints)
  int* cur   = (int*)(ws + 31031108);        //     30,016
  int* srt   = (int*)(ws + 31061124);        //  1,920,000
  if (ws_size < (size_t)32981124) return;

  // zero deg + bins (contiguous); off/cur/srt fully overwritten downstream
  hipMemsetAsync(ws + 30851072, 0, 150016, stream);

  k_gather_x<<<3750, 256, 0, stream>>>(node_emb, local_nodes, x_a);
  k_hist_bins<<<1875, 256, 0, stream>>>(edge_index, edge_type, bins);
  k_scan_bins<<<1, 1024, 0, stream>>>(bins, off, cur);
  k_fill<<<1875, 256, 0, stream>>>(edge_index, edge_type, cur, srt, deg);
  k_transposeW<<<2, 256, 0, stream>>>(Wself_w0, Wself_w1, WT0, WT1);

  k_fused<<<NBLK, 256, 0, stream>>>(x_a, W_rel0, WT0, Wself_b0, srt, off, deg, x_b);
  k_fused<<<NBLK, 256, 0, stream>>>(x_b, W_rel1, WT1, Wself_b1, srt, off, deg, x_a);

  k_score<<<1024, 256, 0, stream>>>(x_a, rel_emb, h_loc, r_ids, t_loc, out);
}